// Round 7
// baseline (503.218 us; speedup 1.0000x reference)
//
#include <hip/hip_runtime.h>
#include <hip/hip_bf16.h>

// LocalizedFiltering: two shifted 2-tap causal convs + residual + RMSNorm.
// Fused form: the 2-tap shift is absorbed into K of each GEMM:
//   A2[r+1] = Xbf[r*1024 .. +2048] @ [W1lo;W1hi] + b1        (K=2048, N=512)
//   Zo[u]   = A2f[r*512 .. +1024] @ [W2lo;W2hi] + b2 + x_res (K=1024, N=1024)
// GEMM: 256x256 tile, BK=64, A 3-deep / B 2-deep LDS (160 KB), round-5 schedule
// (single counted vmcnt(4)+barrier per K-tile; A staged 2 tiles ahead).
// Final kernel: pure RMSNorm over Zo.

#define EDIM 1024
#define HDIM 512
#define LSEQ 8192
#define BSEQ 8
#define SEQR 8193                 // L+1
#define MTOT (BSEQ * SEQR)        // 65544 extended rows
#define XROWS 66048               // slack rows (zeroed)

using v8s = __attribute__((ext_vector_type(8))) short;
using v4f = __attribute__((ext_vector_type(4))) float;

__device__ __forceinline__ unsigned short f2b(float f) {
  union { float f; unsigned u; } v; v.f = f;
  unsigned r = v.u + 0x7fffu + ((v.u >> 16) & 1u);   // RNE
  return (unsigned short)(r >> 16);
}
__device__ __forceinline__ float b2f(unsigned short h) {
  union { unsigned u; float f; } v; v.u = ((unsigned)h) << 16; return v.f;
}
__device__ __forceinline__ void gl_lds16(const void* g, void* l) {
  __builtin_amdgcn_global_load_lds((const __attribute__((address_space(1))) void*)g,
                                   (__attribute__((address_space(3))) void*)l, 16, 0, 0);
}

// -------- prep: dst[n][dst_k0+k] = src[k][src_c0+n] (transpose slice -> bf16) --------
__global__ __launch_bounds__(256) void transpose_cat(const float* __restrict__ src, int src_ld,
                                                     int src_c0, unsigned short* __restrict__ dst,
                                                     int dst_ld, int dst_k0) {
  __shared__ float t[64][65];
  const int n0 = blockIdx.x * 64, k0 = blockIdx.y * 64;
  const int tx = threadIdx.x & 63, ty = threadIdx.x >> 6;
#pragma unroll
  for (int yy = 0; yy < 64; yy += 4)
    t[yy + ty][tx] = src[(size_t)(k0 + yy + ty) * src_ld + src_c0 + n0 + tx];
  __syncthreads();
#pragma unroll
  for (int yy = 0; yy < 64; yy += 4)
    dst[(size_t)(n0 + yy + ty) * dst_ld + dst_k0 + k0 + tx] = f2b(t[tx][yy + ty]);
}

// gather the 8 lf2 cache rows as bf16
__global__ void prep_small(const float* __restrict__ lf2, const int* __restrict__ preidx,
                           unsigned short* __restrict__ c2b) {
  const int tid = threadIdx.x;  // 512
#pragma unroll
  for (int b = 0; b < BSEQ; ++b)
    c2b[b * HDIM + tid] = f2b(lf2[(size_t)preidx[b] * HDIM + tid]);
}

// -------- cvt: bf16 extended-A (cache row + shifted tokens, zero pad to XROWS) --------
__global__ __launch_bounds__(256) void cvt_full(const float* __restrict__ inputs,
                                                const float* __restrict__ lf1,
                                                const int* __restrict__ preidx,
                                                unsigned short* __restrict__ Xbf) {
  const int r = blockIdx.x * 4 + (threadIdx.x >> 6);   // 0..XROWS-1
  const int lane = threadIdx.x & 63;
  unsigned short* dst = Xbf + (size_t)r * EDIM;
  if (r >= MTOT) {
#pragma unroll
    for (int c = lane * 4; c < EDIM; c += 256)
      *(ushort4*)&dst[c] = (ushort4){0, 0, 0, 0};
    return;
  }
  const int b = r / SEQR, rr = r % SEQR;
  const float* src = (rr == 0) ? (lf1 + (size_t)preidx[b] * EDIM)
                               : (inputs + (size_t)(b * LSEQ + rr - 1) * EDIM);
#pragma unroll
  for (int c = lane * 4; c < EDIM; c += 256) {
    const float4 v = *(const float4*)(src + c);
    *(ushort4*)&dst[c] = (ushort4){f2b(v.x), f2b(v.y), f2b(v.z), f2b(v.w)};
  }
}

// -------- fixup: cache rows of A2 (blk 7) + tail rows 65537..65543 (blk 0..6) --------
__global__ __launch_bounds__(512) void fixup_full(const unsigned short* __restrict__ Xbf,
                                                  const unsigned short* __restrict__ W1c,
                                                  const float* __restrict__ b1,
                                                  const unsigned short* __restrict__ c2b,
                                                  unsigned short* __restrict__ A2) {
  const int blk = blockIdx.x;        // 0..7
  const int tid = threadIdx.x;       // 512
  if (blk == 7) {
#pragma unroll
    for (int b = 0; b < BSEQ; ++b)
      A2[(size_t)(b * SEQR) * HDIM + tid] = c2b[b * HDIM + tid];
    return;
  }
  // ext row r: A2[r+1][tid] = dot(Xbf_flat[r*1024 .. +2048], W1c[tid]) + b1[tid]
  const int r = 65536 + blk;                         // 65536..65542 (< MTOT-1)
  const unsigned short* a = Xbf + (size_t)r * EDIM;  // 2048 contiguous bf16
  const unsigned short* wrow = W1c + (size_t)tid * 2048;
  float s = 0.f;
  for (int k = 0; k < 2048; k += 8) {
    const v8s av = *(const v8s*)&a[k];
    const v8s wv = *(const v8s*)&wrow[k];
#pragma unroll
    for (int j = 0; j < 8; ++j)
      s += b2f((unsigned short)av[j]) * b2f((unsigned short)wv[j]);
  }
  A2[(size_t)(r + 1) * HDIM + tid] = f2b(s + b1[tid]);
}

// ======= 256x256 GEMM, BK=64, 8 waves (2m x 4n), A 3-deep / B 2-deep, 1 wait/tile =======
// C[M][N] = A'[M][K] @ B[N][K]^T. A' rows overlap in memory: row u starts at
// A + umap(u)*LDA. AMAP: umap(u)=u+(u>>13). SHIFTC: C row = u+1, +bias.
// RESID: C[u] += bias[col] + Xbf[u + (u>>13) + 1][col]  (residual fused).
#define PHASE(p, boA_)                                                                 \
  {                                                                                    \
    v8s af[2][2];                                                                      \
    _Pragma("unroll") for (int m2 = 0; m2 < 2; ++m2)                                   \
    _Pragma("unroll") for (int kx = 0; kx < 2; ++kx)                                   \
      af[m2][kx] = *(const v8s*)&lds[(boA_) + ((2 * (p) + m2) * 32 + wm * 16 + lr) * 64 + \
                                     (((kx * 4 + lk) ^ ra7) << 3)];                    \
    __builtin_amdgcn_s_setprio(1);                                                     \
    _Pragma("unroll") for (int m2 = 0; m2 < 2; ++m2)                                   \
    _Pragma("unroll") for (int nc = 0; nc < 4; ++nc)                                   \
    _Pragma("unroll") for (int kx = 0; kx < 2; ++kx)                                   \
      acc[2 * (p) + m2][nc] = __builtin_amdgcn_mfma_f32_16x16x32_bf16(                 \
          af[m2][kx], bf[nc][kx], acc[2 * (p) + m2][nc], 0, 0, 0);                     \
    __builtin_amdgcn_s_setprio(0);                                                     \
  }

#define LOAD_BFR(boB_)                                                                 \
  _Pragma("unroll") for (int nc = 0; nc < 4; ++nc)                                     \
  _Pragma("unroll") for (int kx = 0; kx < 2; ++kx)                                     \
    bf[nc][kx] = *(const v8s*)&lds[(boB_) + (nc * 64 + wn * 16 + lr) * 64 +            \
                                   (((kx * 4 + lk) ^ ra7) << 3)];

template <int K, int LDA, int NT, bool AMAP, bool SHIFTC, bool RESID>
__global__ __launch_bounds__(512, 2) void gemm3b(const unsigned short* __restrict__ A,
                                                 const unsigned short* __restrict__ B,
                                                 unsigned short* __restrict__ C,
                                                 const float* __restrict__ bias,
                                                 const unsigned short* __restrict__ Xres,
                                                 int q, int r) {
  __shared__ __align__(16) unsigned short lds[81920];  // A:3x16384 @0, B:2x16384 @49152
  constexpr int NTILES = K / 64;
  constexpr int N = NT * 256;
  const int h = blockIdx.x;
  const int xcd = h & 7, idx = h >> 3;
  const int tsw = (xcd < r ? xcd * (q + 1) : r * (q + 1) + (xcd - r) * q) + idx;
  const int mt = tsw / NT, nt = tsw % NT;   // n-fast: neighbors share A m-panel
  const size_t m0 = (size_t)mt * 256, n0 = (size_t)nt * 256;
  const int tid = threadIdx.x;
  const int w = tid >> 6, lane = tid & 63;
  const int wm = w >> 2, wn = w & 3;
  const int lr = lane & 15, lk = lane >> 4;
  const int ra7 = lr & 7;
  const int srow = tid >> 3, slot = tid & 7;
  const int gslot = slot ^ (srow & 7);            // pre-swizzled global 16B-slot
  const int dA = srow * 64 + slot * 8;            // linear LDS dest = wavebase + lane*16B
  const unsigned short* bSrc = B + (size_t)(n0 + srow) * K + gslot * 8;

  auto stageA = [&](int dst, int hh, int tt) {
#pragma unroll
    for (int hf = 0; hf < 2; ++hf) {
      int u = (int)m0 + hh * 128 + hf * 64 + srow;
      if constexpr (AMAP) u += (u >> 13);
      gl_lds16(A + (size_t)u * LDA + tt * 64 + gslot * 8,
               &lds[dst + hh * 8192 + hf * 4096 + dA]);
    }
  };
  auto stageB = [&](int dst, int hh, int tt) {
    const unsigned short* s = bSrc + (size_t)hh * 128 * K + (size_t)tt * 64;
    unsigned short* d = &lds[dst + hh * 8192 + dA];
    gl_lds16(s, d);
    gl_lds16(s + (size_t)64 * K, d + 4096);
  };

  v4f acc[8][4];
#pragma unroll
  for (int i = 0; i < 8; ++i)
#pragma unroll
    for (int j = 0; j < 4; ++j) acc[i][j] = (v4f){0.f, 0.f, 0.f, 0.f};

  // prologue: B(0) -> bufB0, A(0) -> bufA0, A(1) -> bufA1; leave A(1) in flight
  stageB(49152, 0, 0); stageB(49152, 1, 0);
  stageA(0, 0, 0);     stageA(0, 1, 0);
  stageA(16384, 0, 1); stageA(16384, 1, 1);
  asm volatile("s_waitcnt vmcnt(4)" ::: "memory");
  __builtin_amdgcn_s_barrier();

  int boA = 0, soA = 32768;        // read / stage A buffer offsets (elements)
  int boB = 49152, sB = 65536;     // read / stage B buffer offsets
#pragma unroll 1
  for (int t0 = 0; t0 < NTILES - 2; ++t0) {
    v8s bf[4][2];
    stageB(sB, 0, t0 + 1);         // B one tile ahead (L2-resident weights)
    LOAD_BFR(boB)
    PHASE(0, boA)
    stageB(sB, 1, t0 + 1);
    PHASE(1, boA)
    stageA(soA, 0, t0 + 2);        // A two tiles ahead (HBM latency cover)
    PHASE(2, boA)
    stageA(soA, 1, t0 + 2);
    PHASE(3, boA)
    // drain B(t0+1) and A(t0+1); leave A(t0+2)'s 4 loads in flight
    asm volatile("s_waitcnt vmcnt(4)" ::: "memory");
    __builtin_amdgcn_s_barrier();
    const int nboA = (boA == 32768) ? 0 : boA + 16384;
    soA = boA; boA = nboA;
    const int tmp = boB; boB = sB; sB = tmp;
  }
  { // tile NTILES-2: stage last B only; full drain at end
    v8s bf[4][2];
    stageB(sB, 0, NTILES - 1);
    LOAD_BFR(boB)
    PHASE(0, boA)
    stageB(sB, 1, NTILES - 1);
    PHASE(1, boA)
    PHASE(2, boA)
    PHASE(3, boA)
    asm volatile("s_waitcnt vmcnt(0)" ::: "memory");
    __builtin_amdgcn_s_barrier();
    boA = (boA == 32768) ? 0 : boA + 16384;
    const int tmp = boB; boB = sB; sB = tmp;
  }
  { // tile NTILES-1: everything resident
    v8s bf[4][2];
    LOAD_BFR(boB)
    PHASE(0, boA) PHASE(1, boA) PHASE(2, boA) PHASE(3, boA)
  }

#pragma unroll
  for (int mr = 0; mr < 8; ++mr)
#pragma unroll
    for (int nc = 0; nc < 4; ++nc) {
      const size_t col = n0 + nc * 64 + wn * 16 + lr;
      float bv = 0.f;
      if constexpr (SHIFTC || RESID) bv = bias[col];
#pragma unroll
      for (int g = 0; g < 4; ++g) {
        const size_t row = m0 + mr * 32 + wm * 16 + lk * 4 + g;
        if constexpr (RESID) {
          const size_t rx = row + (row >> 13) + 1;          // token's ext row in Xbf
          const float x = acc[mr][nc][g] + bv + b2f(Xres[rx * EDIM + col]);
          C[row * N + col] = f2b(x);
        } else {
          C[(row + (SHIFTC ? 1 : 0)) * N + col] = f2b(acc[mr][nc][g] + bv);
        }
      }
    }
}

// ---------- final: pure RMSNorm over Zo (x already has b2 + residual) ----------
__global__ __launch_bounds__(256) void rms_final(const unsigned short* __restrict__ Zo,
                                                 const float* __restrict__ lnw,
                                                 float* __restrict__ out) {
  const int u = blockIdx.x;                       // token id 0..65535
  const int tid = threadIdx.x;
  const int j0 = tid * 4;

  const ushort4 z = *(const ushort4*)&Zo[(size_t)u * EDIM + j0];
  const float4 lw = *(const float4*)&lnw[j0];
  const float x0 = b2f(z.x), x1 = b2f(z.y), x2 = b2f(z.z), x3 = b2f(z.w);

  float ss = x0 * x0 + x1 * x1 + x2 * x2 + x3 * x3;
#pragma unroll
  for (int o = 32; o > 0; o >>= 1) ss += __shfl_xor(ss, o, 64);
  __shared__ float sp[4];
  if ((tid & 63) == 0) sp[tid >> 6] = ss;
  __syncthreads();
  const float tot = sp[0] + sp[1] + sp[2] + sp[3];
  const float scale = rsqrtf(tot * (1.0f / EDIM) + 1e-6f);

  float4 o4;
  o4.x = x0 * scale * lw.x; o4.y = x1 * scale * lw.y;
  o4.z = x2 * scale * lw.z; o4.w = x3 * scale * lw.w;
  *(float4*)&out[(size_t)u * EDIM + j0] = o4;
}

// -------------------------------- launch --------------------------------
extern "C" void kernel_launch(void* const* d_in, const int* in_sizes, int n_in,
                              void* d_out, int out_size, void* d_ws, size_t ws_size,
                              hipStream_t stream) {
  const float* inputs = (const float*)d_in[0];
  const float* W1 = (const float*)d_in[1];
  const float* W2 = (const float*)d_in[2];
  const float* b1 = (const float*)d_in[3];
  const float* b2 = (const float*)d_in[4];
  const float* lnw = (const float*)d_in[5];
  const float* lf1 = (const float*)d_in[6];
  const float* lf2 = (const float*)d_in[7];
  const int* preidx = (const int*)d_in[8];
  float* out = (float*)d_out;

  char* ws = (char*)d_ws;
  unsigned short* Xbf = (unsigned short*)(ws);                 // XROWS x 1024 = 135,266,304 B
  unsigned short* A2  = (unsigned short*)(ws + 135266304ULL);  // XROWS x  512 =  67,633,152 B
  unsigned short* Zo  = (unsigned short*)(ws + 202899456ULL);  // 65536 x 1024 = 134,217,728 B
  unsigned short* W1c = (unsigned short*)(ws + 337117184ULL);  //  512 x 2048 bf16
  unsigned short* W2c = (unsigned short*)(ws + 339214336ULL);  // 1024 x 1024 bf16
  unsigned short* c2b = (unsigned short*)(ws + 341311488ULL);  // 8 x 512
  // total ws use: ~341 MB

  // W1c[n][k] = k<1024 ? W1[k][n] : W1[k-1024][512+n]   (512 x 2048)
  transpose_cat<<<dim3(8, 16), 256, 0, stream>>>(W1, 1024, 0, W1c, 2048, 0);
  transpose_cat<<<dim3(8, 16), 256, 0, stream>>>(W1, 1024, 512, W1c, 2048, 1024);
  // W2c[n][k] = k<512 ? W2[k][n] : W2[k-512][1024+n]    (1024 x 1024)
  transpose_cat<<<dim3(16, 8), 256, 0, stream>>>(W2, 2048, 0, W2c, 1024, 0);
  transpose_cat<<<dim3(16, 8), 256, 0, stream>>>(W2, 2048, 1024, W2c, 1024, 512);
  prep_small<<<1, 512, 0, stream>>>(lf2, preidx, c2b);

  cvt_full<<<XROWS / 4, 256, 0, stream>>>(inputs, lf1, preidx, Xbf);
  // GEMM1: M=65536 (256 m-tiles) x N=512 (2 n-tiles) -> 512 blocks; q=64, r=0
  gemm3b<2048, 1024, 2, false, true, false>
      <<<512, 512, 0, stream>>>(Xbf, W1c, A2, b1, nullptr, 64, 0);
  fixup_full<<<8, 512, 0, stream>>>(Xbf, W1c, b1, c2b, A2);
  // GEMM2: M=65536 (256 m-tiles) x N=1024 (4 n-tiles) -> 1024 blocks; q=128, r=0
  // residual + b2 fused into C-write
  gemm3b<1024, 512, 4, true, false, true>
      <<<1024, 512, 0, stream>>>(A2, W2c, Zo, b2, Xbf, 128, 0);
  rms_final<<<BSEQ * LSEQ, 256, 0, stream>>>(Zo, lnw, out);
}

// Round 8
// 471.489 us; speedup vs baseline: 1.0673x; 1.0673x over previous
//
#include <hip/hip_runtime.h>
#include <hip/hip_bf16.h>

// LocalizedFiltering: two shifted 2-tap causal convs + residual + RMSNorm.
// Fused-K form: A'[u] = U[u] ‖ U[u+1] (U = Xbf for GEMM1, A2 for GEMM2):
//   A2[u+1] = Xbf'[u] @ [W1lo;W1hi] + b1        (K=2048, N=512)
//   Zo[u]   = A2'[u]  @ [W2lo;W2hi]             (K=1024, N=1024), then +b2+res+RMS.
// GEMM: 256x256 tile, BK=64, K-tiles processed in PAIRS (t, t+NH) sharing one
// 257-row underlying A slice (A staging halved). Waits: vmcnt(4) mid-pair,
// vmcnt(0) at pair end (uniform; wave-0 tail instr safe under oldest-first).

#define EDIM 1024
#define HDIM 512
#define LSEQ 8192
#define BSEQ 8
#define SEQR 8193                 // L+1
#define MTOT (BSEQ * SEQR)        // 65544 extended rows
#define XROWS 66048               // slack rows (zeroed)

using v8s = __attribute__((ext_vector_type(8))) short;
using v4f = __attribute__((ext_vector_type(4))) float;

__device__ __forceinline__ unsigned short f2b(float f) {
  union { float f; unsigned u; } v; v.f = f;
  unsigned r = v.u + 0x7fffu + ((v.u >> 16) & 1u);   // RNE
  return (unsigned short)(r >> 16);
}
__device__ __forceinline__ float b2f(unsigned short h) {
  union { unsigned u; float f; } v; v.u = ((unsigned)h) << 16; return v.f;
}
__device__ __forceinline__ void gl_lds16(const void* g, void* l) {
  __builtin_amdgcn_global_load_lds((const __attribute__((address_space(1))) void*)g,
                                   (__attribute__((address_space(3))) void*)l, 16, 0, 0);
}

// -------- merged prep: W1c/W2c transposed-cat bf16 weights + c2b gather (1 launch) --------
__device__ __forceinline__ void trns64(const float* __restrict__ src, int src_ld, int src_c0,
                                       unsigned short* __restrict__ dst, int dst_ld, int dst_k0,
                                       int n0, int k0, float (*t)[65], int tx, int ty) {
#pragma unroll
  for (int yy = 0; yy < 64; yy += 4)
    t[yy + ty][tx] = src[(size_t)(k0 + yy + ty) * src_ld + src_c0 + n0 + tx];
  __syncthreads();
#pragma unroll
  for (int yy = 0; yy < 64; yy += 4)
    dst[(size_t)(n0 + yy + ty) * dst_ld + dst_k0 + k0 + tx] = f2b(t[tx][yy + ty]);
}

__global__ __launch_bounds__(256) void prep_all(const float* __restrict__ W1,
                                                const float* __restrict__ W2,
                                                const float* __restrict__ lf2,
                                                const int* __restrict__ preidx,
                                                unsigned short* __restrict__ W1c,
                                                unsigned short* __restrict__ W2c,
                                                unsigned short* __restrict__ c2b) {
  __shared__ float t[64][65];
  const int bk = blockIdx.x;
  const int tid = threadIdx.x;
  if (bk == 512) {                       // c2b: 8 rows x 512 cols
    for (int c = tid; c < HDIM; c += 256)
#pragma unroll
      for (int b = 0; b < BSEQ; ++b)
        c2b[b * HDIM + c] = f2b(lf2[(size_t)preidx[b] * HDIM + c]);
    return;
  }
  const int tx = tid & 63, ty = tid >> 6;
  const int which = bk >> 7, s = bk & 127;
  if (which == 0)       trns64(W1, 1024, 0,    W1c, 2048, 0,    (s & 7) * 64,  (s >> 3) * 64, t, tx, ty);
  else if (which == 1)  trns64(W1, 1024, 512,  W1c, 2048, 1024, (s & 7) * 64,  (s >> 3) * 64, t, tx, ty);
  else if (which == 2)  trns64(W2, 2048, 0,    W2c, 1024, 0,    (s & 15) * 64, (s >> 4) * 64, t, tx, ty);
  else                  trns64(W2, 2048, 1024, W2c, 1024, 512,  (s & 15) * 64, (s >> 4) * 64, t, tx, ty);
}

// -------- cvt: bf16 extended-A (cache row + shifted tokens, zero pad to XROWS) --------
__global__ __launch_bounds__(256) void cvt_full(const float* __restrict__ inputs,
                                                const float* __restrict__ lf1,
                                                const int* __restrict__ preidx,
                                                unsigned short* __restrict__ Xbf) {
  const int r = blockIdx.x * 4 + (threadIdx.x >> 6);   // 0..XROWS-1
  const int lane = threadIdx.x & 63;
  unsigned short* dst = Xbf + (size_t)r * EDIM;
  if (r >= MTOT) {
#pragma unroll
    for (int c = lane * 4; c < EDIM; c += 256)
      *(ushort4*)&dst[c] = (ushort4){0, 0, 0, 0};
    return;
  }
  const int b = r / SEQR, rr = r % SEQR;
  const float* src = (rr == 0) ? (lf1 + (size_t)preidx[b] * EDIM)
                               : (inputs + (size_t)(b * LSEQ + rr - 1) * EDIM);
#pragma unroll
  for (int c = lane * 4; c < EDIM; c += 256) {
    const float4 v = *(const float4*)(src + c);
    *(ushort4*)&dst[c] = (ushort4){f2b(v.x), f2b(v.y), f2b(v.z), f2b(v.w)};
  }
}

// -------- fixup: cache rows of A2 (blk 7) + tail rows 65537..65543 (blk 0..6) --------
__global__ __launch_bounds__(512) void fixup_full(const unsigned short* __restrict__ Xbf,
                                                  const unsigned short* __restrict__ W1c,
                                                  const float* __restrict__ b1,
                                                  const unsigned short* __restrict__ c2b,
                                                  unsigned short* __restrict__ A2) {
  const int blk = blockIdx.x;        // 0..7
  const int tid = threadIdx.x;       // 512
  if (blk == 7) {
#pragma unroll
    for (int b = 0; b < BSEQ; ++b)
      A2[(size_t)(b * SEQR) * HDIM + tid] = c2b[b * HDIM + tid];
    return;
  }
  const int r = 65536 + blk;                         // ext rows 65536..65542
  const unsigned short* a = Xbf + (size_t)r * EDIM;  // 2048 contiguous bf16
  const unsigned short* wrow = W1c + (size_t)tid * 2048;
  float s = 0.f;
  for (int k = 0; k < 2048; k += 8) {
    const v8s av = *(const v8s*)&a[k];
    const v8s wv = *(const v8s*)&wrow[k];
#pragma unroll
    for (int j = 0; j < 8; ++j)
      s += b2f((unsigned short)av[j]) * b2f((unsigned short)wv[j]);
  }
  A2[(size_t)(r + 1) * HDIM + tid] = f2b(s + b1[tid]);
}

// ======= paired-K 256x256 GEMM, BK=64, 8 waves (2m x 4n) =======
// LDS: A pair-bufs [258r x 64c] @0/@16512 (elems); B step-bufs @33024 (alpha), @49408 (beta).
// Pair i: step alpha = K-tile i (LDS A rows +0), step beta = K-tile i+NH (rows +1).
#define PHASE(p, boA_, off_, ra_)                                                      \
  {                                                                                    \
    v8s af[2][2];                                                                      \
    _Pragma("unroll") for (int m2 = 0; m2 < 2; ++m2)                                   \
    _Pragma("unroll") for (int kx = 0; kx < 2; ++kx)                                   \
      af[m2][kx] = *(const v8s*)&lds[(boA_) +                                          \
          ((2 * (p) + m2) * 32 + wm * 16 + lr + (off_)) * 64 +                         \
          (((kx * 4 + lk) ^ (ra_)) << 3)];                                             \
    __builtin_amdgcn_s_setprio(1);                                                     \
    _Pragma("unroll") for (int m2 = 0; m2 < 2; ++m2)                                   \
    _Pragma("unroll") for (int nc = 0; nc < 4; ++nc)                                   \
    _Pragma("unroll") for (int kx = 0; kx < 2; ++kx)                                   \
      acc[2 * (p) + m2][nc] = __builtin_amdgcn_mfma_f32_16x16x32_bf16(                 \
          af[m2][kx], bf[nc][kx], acc[2 * (p) + m2][nc], 0, 0, 0);                     \
    __builtin_amdgcn_s_setprio(0);                                                     \
  }

#define LOAD_BFR(boB_)                                                                 \
  _Pragma("unroll") for (int nc = 0; nc < 4; ++nc)                                     \
  _Pragma("unroll") for (int kx = 0; kx < 2; ++kx)                                     \
    bf[nc][kx] = *(const v8s*)&lds[(boB_) + (nc * 64 + wn * 16 + lr) * 64 +            \
                                   (((kx * 4 + lk) ^ ra7a) << 3)];

#define STEP4(boA_, off_, ra_)                                                         \
  PHASE(0, boA_, off_, ra_) PHASE(1, boA_, off_, ra_)                                  \
  PHASE(2, boA_, off_, ra_) PHASE(3, boA_, off_, ra_)

template <int K, int NT, bool SHIFTC, bool AMAP>
__global__ __launch_bounds__(512, 2) void gemm_pair(const unsigned short* __restrict__ A,
                                                    const unsigned short* __restrict__ B,
                                                    unsigned short* __restrict__ C,
                                                    const float* __restrict__ bias,
                                                    int q, int r) {
  constexpr int NH = K / 128;          // pairs
  constexpr int LDA = K / 2;           // underlying row stride
  constexpr int N = NT * 256;
  constexpr int A0 = 0, A1 = 16512, B_A = 33024, B_B = 49408;   // elem offsets
  __shared__ __align__(16) unsigned short lds[65792];           // 131584 B

  const int h = blockIdx.x;
  const int xcd = h & 7, idx = h >> 3;
  const int tsw = (xcd < r ? xcd * (q + 1) : r * (q + 1) + (xcd - r) * q) + idx;
  const int mt = tsw / NT, nt = tsw % NT;   // n-fast: neighbors share A m-panel
  const size_t m0 = (size_t)mt * 256, n0 = (size_t)nt * 256;
  const int tid = threadIdx.x;
  const int w = tid >> 6, lane = tid & 63;
  const int wm = w >> 2, wn = w & 3;
  const int lr = lane & 15, lk = lane >> 4;
  const int ra7a = lr & 7, ra7b = (lr + 1) & 7;
  const int srow = tid >> 3, slot = tid & 7;
  const int gslot = slot ^ (srow & 7);            // pre-swizzled global 16B-slot
  const int dAB = srow * 64 + slot * 8;           // linear LDS dest = wavebase + lane*16B
  const int aBase = (int)m0 + (AMAP ? ((int)m0 >> 13) : 0);  // underlying base row

  // stage underlying A slice for pair i: rows aBase..aBase+256, cols [i*64, i*64+64)
  auto stageApair = [&](int dstE, int i) {
#pragma unroll
    for (int j = 0; j < 4; ++j) {
      const int rr = j * 64 + (tid >> 3);
      gl_lds16(A + (size_t)(aBase + rr) * LDA + i * 64 + ((tid & 7) ^ (rr & 7)) * 8,
               &lds[dstE + rr * 64 + (tid & 7) * 8]);
    }
    if (tid < 8)   // tail row 256 (wave-0 only; ledger safe: oldest-first retire + vmcnt(0))
      gl_lds16(A + (size_t)(aBase + 256) * LDA + i * 64 + tid * 8,
               &lds[dstE + 256 * 64 + tid * 8]);
  };
  // stage B K-tile t (256 n-rows x 64 cols), hh = row-half
  auto stageB = [&](int dstE, int hh, int t) {
    const unsigned short* s = B + (size_t)(n0 + hh * 128 + srow) * K + t * 64 + gslot * 8;
    unsigned short* d = &lds[dstE + hh * 8192 + dAB];
    gl_lds16(s, d);
    gl_lds16(s + (size_t)64 * K, d + 4096);
  };

  v4f acc[8][4];
#pragma unroll
  for (int i = 0; i < 8; ++i)
#pragma unroll
    for (int j = 0; j < 4; ++j) acc[i][j] = (v4f){0.f, 0.f, 0.f, 0.f};

  // prologue: A(pair 0) + B(alpha 0); full drain
  stageApair(A0, 0);
  stageB(B_A, 0, 0); stageB(B_A, 1, 0);
  asm volatile("s_waitcnt vmcnt(0)" ::: "memory");
  __builtin_amdgcn_s_barrier();

#pragma unroll 1
  for (int i = 0; i < NH - 1; ++i) {
    const int boA = (i & 1) ? A1 : A0;
    const int soA = (i & 1) ? A0 : A1;
    v8s bf[4][2];
    // ---- step alpha (K-tile i): issue B(beta)[4] then A(pair i+1)[4+tail] ----
    stageB(B_B, 0, i + NH); stageB(B_B, 1, i + NH);
    stageApair(soA, i + 1);
    LOAD_BFR(B_A)
    STEP4(boA, 0, ra7a)
    // mid-pair: retire the 4 B(beta) (oldest); A(pair i+1) stays in flight
    asm volatile("s_waitcnt vmcnt(4)" ::: "memory");
    __builtin_amdgcn_s_barrier();
    // ---- step beta (K-tile i+NH): issue B(alpha, i+1)[4] ----
    stageB(B_A, 0, i + 1); stageB(B_A, 1, i + 1);
    LOAD_BFR(B_B)
    STEP4(boA, 1, ra7b)
    // pair end: drain everything (A pair i+1 had a full pair of flight time)
    asm volatile("s_waitcnt vmcnt(0)" ::: "memory");
    __builtin_amdgcn_s_barrier();
  }
  { // last pair (i = NH-1): only B(beta) staged; mid wait MUST be vmcnt(0)
    const int boA = ((NH - 1) & 1) ? A1 : A0;
    v8s bf[4][2];
    stageB(B_B, 0, 2 * NH - 1); stageB(B_B, 1, 2 * NH - 1);
    LOAD_BFR(B_A)
    STEP4(boA, 0, ra7a)
    asm volatile("s_waitcnt vmcnt(0)" ::: "memory");
    __builtin_amdgcn_s_barrier();
    LOAD_BFR(B_B)
    STEP4(boA, 1, ra7b)
  }

#pragma unroll
  for (int mr = 0; mr < 8; ++mr)
#pragma unroll
    for (int nc = 0; nc < 4; ++nc) {
      const size_t col = n0 + nc * 64 + wn * 16 + lr;
      float bv = 0.f;
      if constexpr (SHIFTC) bv = bias[col];
#pragma unroll
      for (int g = 0; g < 4; ++g) {
        const size_t row = m0 + mr * 32 + wm * 16 + lk * 4 + g + (SHIFTC ? 1 : 0);
        C[row * N + col] = f2b(acc[mr][nc][g] + bv);
      }
    }
}

// ---------- epilogue: + b2 + residual(bf16 Xbf) + RMSNorm, one block per token ----------
__global__ __launch_bounds__(256) void epilogue_full(
    const unsigned short* __restrict__ Zo, const unsigned short* __restrict__ Xbf,
    const float* __restrict__ b2, const float* __restrict__ lnw,
    float* __restrict__ out) {
  const int u = blockIdx.x;                       // token id 0..65535
  const size_t rx = (size_t)u + (u >> 13) + 1;    // token's ext row in Xbf
  const int tid = threadIdx.x;
  const int j0 = tid * 4;

  const ushort4 z = *(const ushort4*)&Zo[(size_t)u * EDIM + j0];
  const ushort4 xb = *(const ushort4*)&Xbf[rx * EDIM + j0];   // = bf16(inputs[token])
  const float4 bb = *(const float4*)&b2[j0];
  const float4 lw = *(const float4*)&lnw[j0];

  const float x0 = b2f(z.x) + bb.x + b2f(xb.x);
  const float x1 = b2f(z.y) + bb.y + b2f(xb.y);
  const float x2 = b2f(z.z) + bb.z + b2f(xb.z);
  const float x3 = b2f(z.w) + bb.w + b2f(xb.w);

  float ss = x0 * x0 + x1 * x1 + x2 * x2 + x3 * x3;
#pragma unroll
  for (int o = 32; o > 0; o >>= 1) ss += __shfl_xor(ss, o, 64);
  __shared__ float sp[4];
  if ((tid & 63) == 0) sp[tid >> 6] = ss;
  __syncthreads();
  const float tot = sp[0] + sp[1] + sp[2] + sp[3];
  const float scale = rsqrtf(tot * (1.0f / EDIM) + 1e-6f);

  float4 o4;
  o4.x = x0 * scale * lw.x; o4.y = x1 * scale * lw.y;
  o4.z = x2 * scale * lw.z; o4.w = x3 * scale * lw.w;
  *(float4*)&out[(size_t)u * EDIM + j0] = o4;
}

// -------------------------------- launch --------------------------------
extern "C" void kernel_launch(void* const* d_in, const int* in_sizes, int n_in,
                              void* d_out, int out_size, void* d_ws, size_t ws_size,
                              hipStream_t stream) {
  const float* inputs = (const float*)d_in[0];
  const float* W1 = (const float*)d_in[1];
  const float* W2 = (const float*)d_in[2];
  const float* b1 = (const float*)d_in[3];
  const float* b2 = (const float*)d_in[4];
  const float* lnw = (const float*)d_in[5];
  const float* lf1 = (const float*)d_in[6];
  const float* lf2 = (const float*)d_in[7];
  const int* preidx = (const int*)d_in[8];
  float* out = (float*)d_out;

  char* ws = (char*)d_ws;
  unsigned short* Xbf = (unsigned short*)(ws);                 // XROWS x 1024 = 135,266,304 B
  unsigned short* A2  = (unsigned short*)(ws + 135266304ULL);  // XROWS x  512 =  67,633,152 B
  unsigned short* Zo  = (unsigned short*)(ws + 202899456ULL);  // 65536 x 1024 = 134,217,728 B
  unsigned short* W1c = (unsigned short*)(ws + 337117184ULL);  //  512 x 2048 bf16
  unsigned short* W2c = (unsigned short*)(ws + 339214336ULL);  // 1024 x 1024 bf16
  unsigned short* c2b = (unsigned short*)(ws + 341311488ULL);  // 8 x 512
  // total ws use: ~341 MB

  prep_all<<<513, 256, 0, stream>>>(W1, W2, lf2, preidx, W1c, W2c, c2b);
  cvt_full<<<XROWS / 4, 256, 0, stream>>>(inputs, lf1, preidx, Xbf);
  // GEMM1: M=65536 x N=512, K=2048 (NH=16 pairs) -> 512 blocks (2 exact waves)
  gemm_pair<2048, 2, true, false><<<512, 512, 0, stream>>>(Xbf, W1c, A2, b1, 64, 0);
  fixup_full<<<8, 512, 0, stream>>>(Xbf, W1c, b1, c2b, A2);
  // GEMM2: M=65536 x N=1024, K=1024 (NH=8 pairs) -> 1024 blocks (4 exact waves)
  gemm_pair<1024, 4, false, true><<<1024, 512, 0, stream>>>(A2, W2c, Zo, nullptr, 128, 0);
  epilogue_full<<<BSEQ * LSEQ, 256, 0, stream>>>(Zo, Xbf, b2, lnw, out);
}